// Round 10
// baseline (71.480 us; speedup 1.0000x reference)
//
#include <hip/hip_runtime.h>
#include <math.h>

#define N      1000           // NCLASSES
#define NTH2   256            // K2: 64 j-lanes x 4 k-quarters
#define MSLICE 16             // K2 blocks per row
#define SROW   1008           // ws row stride (floats); S[0..1000] (guarded)
#define META   (64 * SROW)    // float offset of metadata
// meta: [META+r] int p | [META+64+r] tval | [META+128 + r*16 + m] slice-min
// R8 post-mortem: NO fused last-block-done tail (device-scope fence storm
// cost +11us); kernel boundaries provide cross-block visibility (R9: 68us,
// absmax 0). R10: K1 packs 2 rows/block (16 waves/CU -> hide shuffle-chain
// latency); K2 plain per-slice stores instead of atomicMin.

// ============== K1: sort + prefix-scan + rank, TWO rows per block ===========
// 32 blocks x 1024 threads; half h (waves 0-7 / 8-15) owns row 2*bx+h.
__global__ __launch_bounds__(1024) void k1_sort_scan(
    const float* __restrict__ mat, const int* __restrict__ target,
    float* __restrict__ ws)
{
    __shared__ float sx[2][2][1024];  // [half][buf][pos] double-buffered exchange
    __shared__ float wtot[2][8];
    __shared__ int   cnt_sh[2];

    const int tid  = threadIdx.x;
    const int h    = tid >> 9;        // row half 0/1 (wave-aligned: 8 waves each)
    const int t    = tid & 511;       // thread index within the half
    const int lane = tid & 63;
    const int w    = (tid >> 6) & 7;  // wave within half
    const int i0   = (w << 7) + lane;
    const int i1   = i0 + 64;
    const int r    = (blockIdx.x << 1) | h;
    const float* row = mat + r * N;
    const int   tgt  = target[r];
    const float tval = row[tgt];

    float r0 = row[i0];                          // i0 <= 959 < N
    float r1 = (i1 < N) ? row[i1] : -INFINITY;
    if (t == 0) cnt_sh[h] = 0;

    // stable descending-sort position of the target
    int lc = ((r0 > tval) || (r0 == tval && i0 < tgt))
           + ((r1 > tval) || (r1 == tval && i1 < tgt));
    #pragma unroll
    for (int off = 32; off; off >>= 1) lc += __shfl_down(lc, off);
    __syncthreads();                             // cnt_sh=0 visible
    if (lane == 0 && lc) atomicAdd(&cnt_sh[h], lc);

    // bitonic sort, descending (shuffle j<=32, register j=64, LDS j>=128)
    auto cas_shfl = [&](float& rr, int i, unsigned k, unsigned j) {
        float o = __shfl_xor(rr, (int)j);
        bool lower = ((lane & (int)j) == 0);
        bool desc  = ((i & (int)k) == 0);
        rr = (lower == desc) ? fmaxf(rr, o) : fminf(rr, o);
    };
    #pragma unroll
    for (unsigned k = 2; k <= 64; k <<= 1)
        #pragma unroll
        for (unsigned j = k >> 1; j; j >>= 1) { cas_shfl(r0, i0, k, j); cas_shfl(r1, i1, k, j); }
    int buf = 0;
    #pragma unroll
    for (unsigned k = 128; k <= 1024; k <<= 1) {
        #pragma unroll
        for (unsigned j = k >> 1; j >= 128; j >>= 1) {
            // double-buffer: one barrier per LDS stage
            sx[h][buf][i0] = r0; sx[h][buf][i1] = r1;
            __syncthreads();
            float o0 = sx[h][buf][i0 ^ (int)j], o1 = sx[h][buf][i1 ^ (int)j];
            buf ^= 1;
            bool lower = ((i0 & (int)j) == 0);   // same for i1 (j>=128)
            bool desc  = ((i0 & (int)k) == 0);   // same for i1 (k>=256)
            r0 = (lower == desc) ? fmaxf(r0, o0) : fminf(r0, o0);
            r1 = (lower == desc) ? fmaxf(r1, o1) : fminf(r1, o1);
        }
        {   // j == 64: in-lane register swap
            bool desc = ((i0 & (int)k) == 0);
            float a = fmaxf(r0, r1), b = fminf(r0, r1);
            r0 = desc ? a : b;
            r1 = desc ? b : a;
        }
        #pragma unroll
        for (unsigned j = 32; j; j >>= 1) { cas_shfl(r0, i0, k, j); cas_shfl(r1, i1, k, j); }
    }

    // prefix sums (shuffle scans); -inf pads -> 0
    if (i1 >= N) r1 = 0.0f;
    float incl0 = r0;
    #pragma unroll
    for (int off = 1; off < 64; off <<= 1) {
        float y = __shfl_up(incl0, off);
        if (lane >= off) incl0 += y;
    }
    float tot0 = __shfl(incl0, 63);
    float incl1 = r1;
    #pragma unroll
    for (int off = 1; off < 64; off <<= 1) {
        float y = __shfl_up(incl1, off);
        if (lane >= off) incl1 += y;
    }
    if (lane == 63) wtot[h][w] = incl0 + incl1;
    __syncthreads();
    float base = 0.0f;
    #pragma unroll
    for (int u = 0; u < 8; ++u) { float x = wtot[h][u]; if (u < w) base += x; }

    float* Sg = ws + r * SROW;
    if (t == 0) Sg[0] = 0.0f;
    Sg[i0 + 1] = base + incl0;                      // i0+1 <= 960 < SROW
    if (i1 < N) Sg[i1 + 1] = base + tot0 + incl1;   // only S[1..1000]
    if (t == 0) {
        ((int*)ws)[META + r] = cnt_sh[h];           // p
        ws[META + 64 + r]    = tval;
    }
}

// ===================== K2: min-max at position p ============================
__global__ __launch_bounds__(NTH2) void k2_minmax(
    const float* __restrict__ ws, float* __restrict__ mrs)
{
    __shared__ float Sloc[N];    // S[p+1 .. N]
    __shared__ float rtab[N];    // 1/(d+1)
    __shared__ float maxh[NTH2];

    const int r  = blockIdx.y;
    const int m  = blockIdx.x;
    const int t  = threadIdx.x;
    const int p  = ((const int*)ws)[META + r];
    const int j0 = m * 64;
    if (j0 > p) return;                        // idle slices exit immediately
    const int len = N - p;
    const float* Srow = ws + r * SROW;

    const int jl = t & 63;
    const int j  = j0 + jl;
    const float Sj = (j <= p) ? Srow[j] : 0.0f;   // hoisted global load

    for (int i = t; i < len; i += NTH2) Sloc[i] = Srow[p + 1 + i];
    for (int d = t; d < N; d += NTH2) rtab[d] = 1.0f / (float)(d + 1);
    __syncthreads();

    const int q  = t >> 6;                 // wave-uniform k-quarter
    const int k0 = (q * len) >> 2;
    const int k1 = ((q + 1) * len) >> 2;
    float maxv = -INFINITY;
    if (j <= p) {
        const float* sp = &Sloc[k0];       // wave-uniform addr -> broadcast
        const float* rp = &rtab[p + k0 - j];  // stride-1 across lanes
        float c = 0.5f * (float)(j + p + k0) - (float)N;  // (j+k)/2 - N
        #pragma unroll 8
        for (int it = 0; it < k1 - k0; ++it) {
            float mval = fmaf(sp[it] - Sj, rp[it], c);
            maxv = fmaxf(maxv, mval);
            c += 0.5f;                     // exact (multiples of 0.5)
        }
    }
    maxh[t] = maxv;
    __syncthreads();
    if (t < 64) {                          // combine quarters + min-reduce
        float mv = fmaxf(fmaxf(maxh[t], maxh[t + 64]),
                         fmaxf(maxh[t + 128], maxh[t + 192]));
        float minv = (j0 + t <= p) ? mv : INFINITY;
        #pragma unroll
        for (int off = 32; off; off >>= 1)
            minv = fminf(minv, __shfl_down(minv, off));
        if (t == 0) mrs[r * MSLICE + m] = minv;   // plain per-slice store
    }
}

// ===================== K3: slice-min fold + loss + mean =====================
__global__ __launch_bounds__(64) void k3_loss(
    const float* __restrict__ ws, float* __restrict__ out, int nrows)
{
    const int t = threadIdx.x;            // row index
    float loss = 0.0f;
    if (t < nrows) {
        const int   p    = ((const int*)ws)[META + t];
        const float tval = ws[META + 64 + t];
        const float* slot = ws + META + 128 + t * MSLICE;
        const int nsl = (p >> 6) + 1;     // active slices: j0 = 64m <= p
        float sol = slot[0];
        for (int m = 1; m < nsl; ++m) sol = fminf(sol, slot[m]);
        loss = fmaxf(0.0f, (float)(N - 5 + 1) - (tval - sol));
    }
    #pragma unroll
    for (int off = 32; off; off >>= 1) loss += __shfl_down(loss, off);
    if (t == 0) out[0] = loss / (float)nrows;
}

// ===================== fallback: monolithic (R4) ============================
__global__ __launch_bounds__(512) void topk_loss_mono(
    const float* __restrict__ mat, const int* __restrict__ target,
    float* __restrict__ d_out, int nrows)
{
    __shared__ float S[1025];
    __shared__ float rcp[N];
    __shared__ float sx[1024];
    __shared__ float wtot[8];
    __shared__ float red[8];
    __shared__ int   cnt_sh;

    const int tid  = threadIdx.x;
    const int lane = tid & 63;
    const int w    = tid >> 6;
    const int i0   = (w << 7) + lane;
    const int i1   = i0 + 64;
    const float* row = mat + blockIdx.x * N;
    const int   tgt  = target[blockIdx.x];
    const float tval = row[tgt];

    float r0 = row[i0];
    float r1 = (i1 < N) ? row[i1] : -INFINITY;
    if (tid == 0) cnt_sh = 0;
    rcp[tid] = 1.0f / (float)(tid + 1);
    if (tid + 512 < N) rcp[tid + 512] = 1.0f / (float)(tid + 512 + 1);

    int lc = ((r0 > tval) || (r0 == tval && i0 < tgt))
           + ((r1 > tval) || (r1 == tval && i1 < tgt));
    #pragma unroll
    for (int off = 32; off; off >>= 1) lc += __shfl_down(lc, off);
    __syncthreads();
    if (lane == 0 && lc) atomicAdd(&cnt_sh, lc);

    auto cas_shfl = [&](float& rr, int i, unsigned k, unsigned j) {
        float o = __shfl_xor(rr, (int)j);
        bool lower = ((lane & (int)j) == 0);
        bool desc  = ((i & (int)k) == 0);
        rr = (lower == desc) ? fmaxf(rr, o) : fminf(rr, o);
    };
    #pragma unroll
    for (unsigned k = 2; k <= 64; k <<= 1)
        #pragma unroll
        for (unsigned j = k >> 1; j; j >>= 1) { cas_shfl(r0, i0, k, j); cas_shfl(r1, i1, k, j); }
    #pragma unroll
    for (unsigned k = 128; k <= 1024; k <<= 1) {
        #pragma unroll
        for (unsigned j = k >> 1; j >= 128; j >>= 1) {
            __syncthreads();
            sx[i0] = r0; sx[i1] = r1;
            __syncthreads();
            float o0 = sx[i0 ^ (int)j], o1 = sx[i1 ^ (int)j];
            bool lower = ((i0 & (int)j) == 0);
            bool desc  = ((i0 & (int)k) == 0);
            r0 = (lower == desc) ? fmaxf(r0, o0) : fminf(r0, o0);
            r1 = (lower == desc) ? fmaxf(r1, o1) : fminf(r1, o1);
        }
        {
            bool desc = ((i0 & (int)k) == 0);
            float a = fmaxf(r0, r1), b = fminf(r0, r1);
            r0 = desc ? a : b;
            r1 = desc ? b : a;
        }
        #pragma unroll
        for (unsigned j = 32; j; j >>= 1) { cas_shfl(r0, i0, k, j); cas_shfl(r1, i1, k, j); }
    }

    if (i1 >= N) r1 = 0.0f;
    float incl0 = r0;
    #pragma unroll
    for (int off = 1; off < 64; off <<= 1) {
        float y = __shfl_up(incl0, off);
        if (lane >= off) incl0 += y;
    }
    float tot0 = __shfl(incl0, 63);
    float incl1 = r1;
    #pragma unroll
    for (int off = 1; off < 64; off <<= 1) {
        float y = __shfl_up(incl1, off);
        if (lane >= off) incl1 += y;
    }
    if (lane == 63) wtot[w] = incl0 + incl1;
    __syncthreads();
    float base = 0.0f;
    #pragma unroll
    for (int u = 0; u < 8; ++u) { float t = wtot[u]; if (u < w) base += t; }
    if (tid == 0) S[0] = 0.0f;
    S[i0 + 1] = base + incl0;
    S[i1 + 1] = base + tot0 + incl1;
    __syncthreads();

    const int p   = cnt_sh;
    const int len = N - p;
    float minv = INFINITY;
    for (int j = tid; j <= p; j += 512) {
        const float  Sj = S[j];
        const float* Sp = &S[p + 1];
        const float* rp = &rcp[p - j];
        const float  cj = 0.5f * (float)(j + p) - (float)N;
        float maxv = -INFINITY;
        #pragma unroll 8
        for (int it = 0; it < len; ++it) {
            float mm = fmaf(Sp[it] - Sj, rp[it], cj + 0.5f * (float)it);
            maxv = fmaxf(maxv, mm);
        }
        minv = fminf(minv, maxv);
    }
    #pragma unroll
    for (int off = 32; off; off >>= 1) minv = fminf(minv, __shfl_down(minv, off));
    if (lane == 0) red[w] = minv;
    __syncthreads();
    if (tid == 0) {
        float sol = red[0];
        #pragma unroll
        for (int u = 1; u < 8; ++u) sol = fminf(sol, red[u]);
        float rank_label = tval - sol;
        float loss = fmaxf(0.0f, (float)(N - 5 + 1) - rank_label);
        atomicAdd(d_out, loss / (float)nrows);
    }
}

extern "C" void kernel_launch(void* const* d_in, const int* in_sizes, int n_in,
                              void* d_out, int out_size, void* d_ws, size_t ws_size,
                              hipStream_t stream) {
    (void)n_in;
    const float* mat    = (const float*)d_in[0];
    const int*   target = (const int*)d_in[1];
    float*       out    = (float*)d_out;
    const int    nrows  = in_sizes[1];   // 64

    const size_t need = (size_t)(META + 128 + 64 * MSLICE) * sizeof(float);
    if (nrows == 64 && ws_size >= need) {
        float* ws  = (float*)d_ws;
        float* mrs = ws + META + 128;
        k1_sort_scan<<<nrows / 2, 1024, 0, stream>>>(mat, target, ws);
        dim3 g2(MSLICE, nrows);
        k2_minmax<<<g2, NTH2, 0, stream>>>(ws, mrs);
        k3_loss<<<1, 64, 0, stream>>>(ws, out, nrows);
    } else {
        hipMemsetAsync(out, 0, sizeof(float) * out_size, stream);
        topk_loss_mono<<<nrows, 512, 0, stream>>>(mat, target, out, nrows);
    }
}

// Round 11
// 71.168 us; speedup vs baseline: 1.0044x; 1.0044x over previous
//
#include <hip/hip_runtime.h>
#include <math.h>

#define N      1000           // NCLASSES
#define NTH1   512            // K1: 8 waves; wave w owns positions [128w,128w+128)
#define NTH2   256            // K2: 64 j-lanes x 4 k-quarters
#define MSLICE 16             // K2 blocks per row
#define SROW   1008           // ws row stride (floats); S[0..1000] (guarded)
#define META   (64 * SROW)    // float offset of metadata
// meta: [META+r] int p | [META+64+r] tval | [META+128 + r*16 + m] slice-min
// Journal: R8 -- NO fused last-block-done tail (device-scope fence storm,
// +11us). R10 -- NO multi-row blocks (barrier couples 16 waves, +3.5us).
// R11 -- K2 off the LDS pipe: s_load for uniform S[k], v_rcp for 1/(k-j+1).

// ============== K1: sort + prefix-scan + rank (R9-verified, 68us) ===========
__global__ __launch_bounds__(NTH1) void k1_sort_scan(
    const float* __restrict__ mat, const int* __restrict__ target,
    float* __restrict__ ws)
{
    __shared__ float sx[2][1024];    // double-buffered exchange: 1 barrier/stage
    __shared__ float wtot[8];
    __shared__ int   cnt_sh;

    const int tid  = threadIdx.x;
    const int lane = tid & 63;
    const int w    = tid >> 6;
    const int i0   = (w << 7) + lane;
    const int i1   = i0 + 64;
    const int r    = blockIdx.x;
    const float* row = mat + r * N;
    const int   tgt  = target[r];
    const float tval = row[tgt];

    float r0 = row[i0];                          // i0 <= 959 < N
    float r1 = (i1 < N) ? row[i1] : -INFINITY;
    if (tid == 0) cnt_sh = 0;

    // stable descending-sort position of the target
    int lc = ((r0 > tval) || (r0 == tval && i0 < tgt))
           + ((r1 > tval) || (r1 == tval && i1 < tgt));
    #pragma unroll
    for (int off = 32; off; off >>= 1) lc += __shfl_down(lc, off);
    __syncthreads();                             // cnt_sh=0 visible
    if (lane == 0 && lc) atomicAdd(&cnt_sh, lc);

    // bitonic sort, descending (shuffle j<=32, register j=64, LDS j>=128)
    auto cas_shfl = [&](float& rr, int i, unsigned k, unsigned j) {
        float o = __shfl_xor(rr, (int)j);
        bool lower = ((lane & (int)j) == 0);
        bool desc  = ((i & (int)k) == 0);
        rr = (lower == desc) ? fmaxf(rr, o) : fminf(rr, o);
    };
    #pragma unroll
    for (unsigned k = 2; k <= 64; k <<= 1)
        #pragma unroll
        for (unsigned j = k >> 1; j; j >>= 1) { cas_shfl(r0, i0, k, j); cas_shfl(r1, i1, k, j); }
    int buf = 0;
    #pragma unroll
    for (unsigned k = 128; k <= 1024; k <<= 1) {
        #pragma unroll
        for (unsigned j = k >> 1; j >= 128; j >>= 1) {
            sx[buf][i0] = r0; sx[buf][i1] = r1;
            __syncthreads();
            float o0 = sx[buf][i0 ^ (int)j], o1 = sx[buf][i1 ^ (int)j];
            buf ^= 1;
            bool lower = ((i0 & (int)j) == 0);   // same for i1 (j>=128)
            bool desc  = ((i0 & (int)k) == 0);   // same for i1 (k>=256)
            r0 = (lower == desc) ? fmaxf(r0, o0) : fminf(r0, o0);
            r1 = (lower == desc) ? fmaxf(r1, o1) : fminf(r1, o1);
        }
        {   // j == 64: in-lane register swap
            bool desc = ((i0 & (int)k) == 0);
            float a = fmaxf(r0, r1), b = fminf(r0, r1);
            r0 = desc ? a : b;
            r1 = desc ? b : a;
        }
        #pragma unroll
        for (unsigned j = 32; j; j >>= 1) { cas_shfl(r0, i0, k, j); cas_shfl(r1, i1, k, j); }
    }

    // prefix sums (shuffle scans); -inf pads -> 0
    if (i1 >= N) r1 = 0.0f;
    float incl0 = r0;
    #pragma unroll
    for (int off = 1; off < 64; off <<= 1) {
        float y = __shfl_up(incl0, off);
        if (lane >= off) incl0 += y;
    }
    float tot0 = __shfl(incl0, 63);
    float incl1 = r1;
    #pragma unroll
    for (int off = 1; off < 64; off <<= 1) {
        float y = __shfl_up(incl1, off);
        if (lane >= off) incl1 += y;
    }
    if (lane == 63) wtot[w] = incl0 + incl1;
    __syncthreads();
    float base = 0.0f;
    #pragma unroll
    for (int u = 0; u < 8; ++u) { float t = wtot[u]; if (u < w) base += t; }

    float* Sg = ws + r * SROW;
    if (tid == 0) Sg[0] = 0.0f;
    Sg[i0 + 1] = base + incl0;                      // i0+1 <= 960 < SROW
    if (i1 < N) Sg[i1 + 1] = base + tot0 + incl1;   // only S[1..1000]
    if (tid == 0) {
        ((int*)ws)[META + r] = cnt_sh;              // p
        ws[META + 64 + r]    = tval;
    }
}

// ============ K2: min-max at position p -- scalar-path inner loop ===========
__global__ __launch_bounds__(NTH2) void k2_minmax(
    const float* __restrict__ ws, float* __restrict__ mrs)
{
    __shared__ float maxh[NTH2];

    const int r  = blockIdx.y;
    const int m  = blockIdx.x;
    const int t  = threadIdx.x;
    // force wave-uniform p so S[k] addressing scalarizes to s_load
    const int p  = __builtin_amdgcn_readfirstlane(((const int*)ws)[META + r]);
    const int j0 = m * 64;
    if (j0 > p) return;                        // idle slices exit immediately
    const int len = N - p;
    const float* Srow = ws + r * SROW;

    const int jl = t & 63;
    const int j  = j0 + jl;
    const float Sj = (j <= p) ? Srow[j] : 0.0f;   // per-lane, loaded once

    const int q  = t >> 6;                 // wave-uniform k-quarter
    const int k0 = (q * len) >> 2;
    const int k1 = ((q + 1) * len) >> 2;
    float maxv = -INFINITY;
    if (j <= p) {
        const float* su = Srow + p + 1 + k0;   // wave-uniform -> s_load path
        float ld = (float)(p + k0 + 1 - j);    // k-j+1 at k=p+k0 (exact ints)
        float c  = 0.5f * (float)(j + p + k0) - (float)N;  // (j+k)/2 - N
        #pragma unroll 8
        for (int it = 0; it < k1 - k0; ++it) {
            float rc   = __builtin_amdgcn_rcpf(ld);    // ~1e-7 rel; VALU pipe
            float mval = fmaf(su[it] - Sj, rc, c);
            maxv = fmaxf(maxv, mval);
            ld += 1.0f;                        // exact
            c  += 0.5f;                        // exact
        }
    }
    maxh[t] = maxv;
    __syncthreads();
    if (t < 64) {                          // combine quarters + min-reduce
        float mv = fmaxf(fmaxf(maxh[t], maxh[t + 64]),
                         fmaxf(maxh[t + 128], maxh[t + 192]));
        float minv = (j0 + t <= p) ? mv : INFINITY;
        #pragma unroll
        for (int off = 32; off; off >>= 1)
            minv = fminf(minv, __shfl_down(minv, off));
        if (t == 0) mrs[r * MSLICE + m] = minv;   // plain per-slice store
    }
}

// ===================== K3: slice-min fold + loss + mean =====================
__global__ __launch_bounds__(64) void k3_loss(
    const float* __restrict__ ws, float* __restrict__ out, int nrows)
{
    const int t = threadIdx.x;            // row index
    float loss = 0.0f;
    if (t < nrows) {
        const int   p    = ((const int*)ws)[META + t];
        const float tval = ws[META + 64 + t];
        const float* slot = ws + META + 128 + t * MSLICE;
        const int nsl = (p >> 6) + 1;     // active slices: j0 = 64m <= p
        float sol = slot[0];
        for (int m = 1; m < nsl; ++m) sol = fminf(sol, slot[m]);
        loss = fmaxf(0.0f, (float)(N - 5 + 1) - (tval - sol));
    }
    #pragma unroll
    for (int off = 32; off; off >>= 1) loss += __shfl_down(loss, off);
    if (t == 0) out[0] = loss / (float)nrows;
}

// ===================== fallback: monolithic (R4) ============================
__global__ __launch_bounds__(512) void topk_loss_mono(
    const float* __restrict__ mat, const int* __restrict__ target,
    float* __restrict__ d_out, int nrows)
{
    __shared__ float S[1025];
    __shared__ float rcp[N];
    __shared__ float sx[1024];
    __shared__ float wtot[8];
    __shared__ float red[8];
    __shared__ int   cnt_sh;

    const int tid  = threadIdx.x;
    const int lane = tid & 63;
    const int w    = tid >> 6;
    const int i0   = (w << 7) + lane;
    const int i1   = i0 + 64;
    const float* row = mat + blockIdx.x * N;
    const int   tgt  = target[blockIdx.x];
    const float tval = row[tgt];

    float r0 = row[i0];
    float r1 = (i1 < N) ? row[i1] : -INFINITY;
    if (tid == 0) cnt_sh = 0;
    rcp[tid] = 1.0f / (float)(tid + 1);
    if (tid + 512 < N) rcp[tid + 512] = 1.0f / (float)(tid + 512 + 1);

    int lc = ((r0 > tval) || (r0 == tval && i0 < tgt))
           + ((r1 > tval) || (r1 == tval && i1 < tgt));
    #pragma unroll
    for (int off = 32; off; off >>= 1) lc += __shfl_down(lc, off);
    __syncthreads();
    if (lane == 0 && lc) atomicAdd(&cnt_sh, lc);

    auto cas_shfl = [&](float& rr, int i, unsigned k, unsigned j) {
        float o = __shfl_xor(rr, (int)j);
        bool lower = ((lane & (int)j) == 0);
        bool desc  = ((i & (int)k) == 0);
        rr = (lower == desc) ? fmaxf(rr, o) : fminf(rr, o);
    };
    #pragma unroll
    for (unsigned k = 2; k <= 64; k <<= 1)
        #pragma unroll
        for (unsigned j = k >> 1; j; j >>= 1) { cas_shfl(r0, i0, k, j); cas_shfl(r1, i1, k, j); }
    #pragma unroll
    for (unsigned k = 128; k <= 1024; k <<= 1) {
        #pragma unroll
        for (unsigned j = k >> 1; j >= 128; j >>= 1) {
            __syncthreads();
            sx[i0] = r0; sx[i1] = r1;
            __syncthreads();
            float o0 = sx[i0 ^ (int)j], o1 = sx[i1 ^ (int)j];
            bool lower = ((i0 & (int)j) == 0);
            bool desc  = ((i0 & (int)k) == 0);
            r0 = (lower == desc) ? fmaxf(r0, o0) : fminf(r0, o0);
            r1 = (lower == desc) ? fmaxf(r1, o1) : fminf(r1, o1);
        }
        {
            bool desc = ((i0 & (int)k) == 0);
            float a = fmaxf(r0, r1), b = fminf(r0, r1);
            r0 = desc ? a : b;
            r1 = desc ? b : a;
        }
        #pragma unroll
        for (unsigned j = 32; j; j >>= 1) { cas_shfl(r0, i0, k, j); cas_shfl(r1, i1, k, j); }
    }

    if (i1 >= N) r1 = 0.0f;
    float incl0 = r0;
    #pragma unroll
    for (int off = 1; off < 64; off <<= 1) {
        float y = __shfl_up(incl0, off);
        if (lane >= off) incl0 += y;
    }
    float tot0 = __shfl(incl0, 63);
    float incl1 = r1;
    #pragma unroll
    for (int off = 1; off < 64; off <<= 1) {
        float y = __shfl_up(incl1, off);
        if (lane >= off) incl1 += y;
    }
    if (lane == 63) wtot[w] = incl0 + incl1;
    __syncthreads();
    float base = 0.0f;
    #pragma unroll
    for (int u = 0; u < 8; ++u) { float t = wtot[u]; if (u < w) base += t; }
    if (tid == 0) S[0] = 0.0f;
    S[i0 + 1] = base + incl0;
    S[i1 + 1] = base + tot0 + incl1;
    __syncthreads();

    const int p   = cnt_sh;
    const int len = N - p;
    float minv = INFINITY;
    for (int j = tid; j <= p; j += 512) {
        const float  Sj = S[j];
        const float* Sp = &S[p + 1];
        const float* rp = &rcp[p - j];
        const float  cj = 0.5f * (float)(j + p) - (float)N;
        float maxv = -INFINITY;
        #pragma unroll 8
        for (int it = 0; it < len; ++it) {
            float mm = fmaf(Sp[it] - Sj, rp[it], cj + 0.5f * (float)it);
            maxv = fmaxf(maxv, mm);
        }
        minv = fminf(minv, maxv);
    }
    #pragma unroll
    for (int off = 32; off; off >>= 1) minv = fminf(minv, __shfl_down(minv, off));
    if (lane == 0) red[w] = minv;
    __syncthreads();
    if (tid == 0) {
        float sol = red[0];
        #pragma unroll
        for (int u = 1; u < 8; ++u) sol = fminf(sol, red[u]);
        float rank_label = tval - sol;
        float loss = fmaxf(0.0f, (float)(N - 5 + 1) - rank_label);
        atomicAdd(d_out, loss / (float)nrows);
    }
}

extern "C" void kernel_launch(void* const* d_in, const int* in_sizes, int n_in,
                              void* d_out, int out_size, void* d_ws, size_t ws_size,
                              hipStream_t stream) {
    (void)n_in;
    const float* mat    = (const float*)d_in[0];
    const int*   target = (const int*)d_in[1];
    float*       out    = (float*)d_out;
    const int    nrows  = in_sizes[1];   // 64

    const size_t need = (size_t)(META + 128 + 64 * MSLICE) * sizeof(float);
    if (nrows == 64 && ws_size >= need) {
        float* ws  = (float*)d_ws;
        float* mrs = ws + META + 128;
        k1_sort_scan<<<nrows, NTH1, 0, stream>>>(mat, target, ws);
        dim3 g2(MSLICE, nrows);
        k2_minmax<<<g2, NTH2, 0, stream>>>(ws, mrs);
        k3_loss<<<1, 64, 0, stream>>>(ws, out, nrows);
    } else {
        hipMemsetAsync(out, 0, sizeof(float) * out_size, stream);
        topk_loss_mono<<<nrows, 512, 0, stream>>>(mat, target, out, nrows);
    }
}

// Round 12
// 69.350 us; speedup vs baseline: 1.0307x; 1.0262x over previous
//
#include <hip/hip_runtime.h>
#include <math.h>

#define N      1000           // NCLASSES
#define NTH1   512            // K1: 8 waves; wave w owns positions [128w,128w+128)
#define NTH2   256            // K2: 64 j-lanes x 4 k-quarters
#define MSLICE 16             // K2 blocks per row
#define SROW   1008           // ws row stride (floats); S[0..1000] only (guarded)
#define META   (64 * SROW)    // float offset of metadata
// meta: [META+r] int p | [META+64+r] tval | [META+128+r] unsigned mr
// Journal (measured, MI355X):
//  R8: NO fused last-block-done tail -- 1024 device-scope fences + one-address
//      atomic storm = +11us vs a separate 1-block K3. Kernel boundaries give
//      the visibility for free.
//  R10: NO multi-row K1 blocks -- __syncthreads couples 16 waves, +3.5us.
//  R11: NO v_rcp in K2 inner loop (quarter-rate transcendental, ~16 cyc/wave
//       vs 5.8 for stride-1 ds_read) and NO scalar-path S[k] loads (L2/K$
//       latency per unroll group beats LDS broadcast): combo cost ~+3us.
//  This file == R9 exactly (best measured: 68.0us, absmax 0).

// ---- order-preserving float<->uint for atomicMin ----
__device__ inline unsigned fkey(float x) {
    unsigned u = __float_as_uint(x);
    return (u & 0x80000000u) ? ~u : (u | 0x80000000u);
}
__device__ inline float fdecode(unsigned u) {
    return __uint_as_float((u & 0x80000000u) ? (u & 0x7FFFFFFFu) : ~u);
}

// ===================== K1: sort + prefix-scan + rank ========================
__global__ __launch_bounds__(NTH1) void k1_sort_scan(
    const float* __restrict__ mat, const int* __restrict__ target,
    float* __restrict__ ws)
{
    __shared__ float sx[2][1024];    // double-buffered exchange: 1 barrier/stage
    __shared__ float wtot[8];
    __shared__ int   cnt_sh;

    const int tid  = threadIdx.x;
    const int lane = tid & 63;
    const int w    = tid >> 6;
    const int i0   = (w << 7) + lane;
    const int i1   = i0 + 64;
    const int r    = blockIdx.x;
    const float* row = mat + r * N;
    const int   tgt  = target[r];
    const float tval = row[tgt];

    float r0 = row[i0];                          // i0 <= 959 < N
    float r1 = (i1 < N) ? row[i1] : -INFINITY;
    if (tid == 0) cnt_sh = 0;

    // stable descending-sort position of the target
    int lc = ((r0 > tval) || (r0 == tval && i0 < tgt))
           + ((r1 > tval) || (r1 == tval && i1 < tgt));
    #pragma unroll
    for (int off = 32; off; off >>= 1) lc += __shfl_down(lc, off);
    __syncthreads();                             // cnt_sh=0 visible
    if (lane == 0 && lc) atomicAdd(&cnt_sh, lc);

    // bitonic sort, descending (shuffle j<=32, register j=64, LDS j>=128)
    auto cas_shfl = [&](float& rr, int i, unsigned k, unsigned j) {
        float o = __shfl_xor(rr, (int)j);
        bool lower = ((lane & (int)j) == 0);
        bool desc  = ((i & (int)k) == 0);
        rr = (lower == desc) ? fmaxf(rr, o) : fminf(rr, o);
    };
    #pragma unroll
    for (unsigned k = 2; k <= 64; k <<= 1)
        #pragma unroll
        for (unsigned j = k >> 1; j; j >>= 1) { cas_shfl(r0, i0, k, j); cas_shfl(r1, i1, k, j); }
    int buf = 0;
    #pragma unroll
    for (unsigned k = 128; k <= 1024; k <<= 1) {
        #pragma unroll
        for (unsigned j = k >> 1; j >= 128; j >>= 1) {
            // double-buffer: stage-s reads of buf retire (lgkmcnt in barrier)
            // before any wave passes stage-(s+1)'s barrier to rewrite it
            sx[buf][i0] = r0; sx[buf][i1] = r1;
            __syncthreads();
            float o0 = sx[buf][i0 ^ (int)j], o1 = sx[buf][i1 ^ (int)j];
            buf ^= 1;
            bool lower = ((i0 & (int)j) == 0);   // same for i1 (j>=128)
            bool desc  = ((i0 & (int)k) == 0);   // same for i1 (k>=256)
            r0 = (lower == desc) ? fmaxf(r0, o0) : fminf(r0, o0);
            r1 = (lower == desc) ? fmaxf(r1, o1) : fminf(r1, o1);
        }
        {   // j == 64: in-lane register swap
            bool desc = ((i0 & (int)k) == 0);
            float a = fmaxf(r0, r1), b = fminf(r0, r1);
            r0 = desc ? a : b;
            r1 = desc ? b : a;
        }
        #pragma unroll
        for (unsigned j = 32; j; j >>= 1) { cas_shfl(r0, i0, k, j); cas_shfl(r1, i1, k, j); }
    }

    // prefix sums (shuffle scans); -inf pads -> 0
    if (i1 >= N) r1 = 0.0f;
    float incl0 = r0;
    #pragma unroll
    for (int off = 1; off < 64; off <<= 1) {
        float y = __shfl_up(incl0, off);
        if (lane >= off) incl0 += y;
    }
    float tot0 = __shfl(incl0, 63);
    float incl1 = r1;
    #pragma unroll
    for (int off = 1; off < 64; off <<= 1) {
        float y = __shfl_up(incl1, off);
        if (lane >= off) incl1 += y;
    }
    if (lane == 63) wtot[w] = incl0 + incl1;
    __syncthreads();
    float base = 0.0f;
    #pragma unroll
    for (int u = 0; u < 8; ++u) { float t = wtot[u]; if (u < w) base += t; }

    float* Sg = ws + r * SROW;
    if (tid == 0) Sg[0] = 0.0f;
    Sg[i0 + 1] = base + incl0;                   // i0+1 <= 960 < SROW
    if (i1 < N) Sg[i1 + 1] = base + tot0 + incl1;   // only S[1..1000]
    if (tid == 0) {
        ((int*)ws)[META + r]            = cnt_sh;        // p
        ws[META + 64 + r]               = tval;
        ((unsigned*)ws)[META + 128 + r] = 0xFFFFFFFFu;   // mr sentinel (+max key)
    }
}

// ===================== K2: min-max at position p ============================
__global__ __launch_bounds__(NTH2) void k2_minmax(
    const float* __restrict__ ws, unsigned* __restrict__ mr)
{
    __shared__ float Sloc[N];    // S[p+1 .. N]
    __shared__ float rtab[N];    // 1/(d+1)
    __shared__ float maxh[NTH2];

    const int r  = blockIdx.y;
    const int m  = blockIdx.x;
    const int t  = threadIdx.x;
    const int p  = ((const int*)ws)[META + r];
    const int j0 = m * 64;
    if (j0 > p) return;                        // idle slices exit immediately
    const int len = N - p;
    const float* Srow = ws + r * SROW;

    const int jl = t & 63;
    const int j  = j0 + jl;
    const float Sj = (j <= p) ? Srow[j] : 0.0f;   // hoisted global load

    for (int i = t; i < len; i += NTH2) Sloc[i] = Srow[p + 1 + i];
    for (int d = t; d < N; d += NTH2) rtab[d] = 1.0f / (float)(d + 1);
    __syncthreads();

    const int q  = t >> 6;                 // wave-uniform k-quarter
    const int k0 = (q * len) >> 2;
    const int k1 = ((q + 1) * len) >> 2;
    float maxv = -INFINITY;
    if (j <= p) {
        const float* sp = &Sloc[k0];       // wave-uniform addr -> broadcast
        const float* rp = &rtab[p + k0 - j];  // stride-1 across lanes
        float c = 0.5f * (float)(j + p + k0) - (float)N;  // (j+k)/2 - N
        #pragma unroll 8
        for (int it = 0; it < k1 - k0; ++it) {
            float mval = fmaf(sp[it] - Sj, rp[it], c);
            maxv = fmaxf(maxv, mval);
            c += 0.5f;                     // exact (multiples of 0.5)
        }
    }
    maxh[t] = maxv;
    __syncthreads();
    if (t < 64) {                          // combine quarters + min-reduce
        float mv = fmaxf(fmaxf(maxh[t], maxh[t + 64]),
                         fmaxf(maxh[t + 128], maxh[t + 192]));
        float minv = (j0 + t <= p) ? mv : INFINITY;
        #pragma unroll
        for (int off = 32; off; off >>= 1)
            minv = fminf(minv, __shfl_down(minv, off));
        if (t == 0) atomicMin(&mr[r], fkey(minv));
    }
}

// ===================== K3: loss + mean ======================================
__global__ __launch_bounds__(64) void k3_loss(
    const unsigned* __restrict__ mr, const float* __restrict__ tv,
    float* __restrict__ out, int nrows)
{
    int t = threadIdx.x;
    float loss = 0.0f;
    if (t < nrows) {
        float sol  = fdecode(mr[t]);
        float rank = tv[t] - sol;
        loss = fmaxf(0.0f, (float)(N - 5 + 1) - rank);
    }
    #pragma unroll
    for (int off = 32; off; off >>= 1) loss += __shfl_down(loss, off);
    if (t == 0) out[0] = loss / (float)nrows;
}

// ===================== fallback: monolithic (R4) ============================
__global__ __launch_bounds__(NTH1) void topk_loss_mono(
    const float* __restrict__ mat, const int* __restrict__ target,
    float* __restrict__ d_out, int nrows)
{
    __shared__ float S[1025];
    __shared__ float rcp[N];
    __shared__ float sx[1024];
    __shared__ float wtot[8];
    __shared__ float red[8];
    __shared__ int   cnt_sh;

    const int tid  = threadIdx.x;
    const int lane = tid & 63;
    const int w    = tid >> 6;
    const int i0   = (w << 7) + lane;
    const int i1   = i0 + 64;
    const float* row = mat + blockIdx.x * N;
    const int   tgt  = target[blockIdx.x];
    const float tval = row[tgt];

    float r0 = row[i0];
    float r1 = (i1 < N) ? row[i1] : -INFINITY;
    if (tid == 0) cnt_sh = 0;
    rcp[tid] = 1.0f / (float)(tid + 1);
    if (tid + NTH1 < N) rcp[tid + NTH1] = 1.0f / (float)(tid + NTH1 + 1);

    int lc = ((r0 > tval) || (r0 == tval && i0 < tgt))
           + ((r1 > tval) || (r1 == tval && i1 < tgt));
    #pragma unroll
    for (int off = 32; off; off >>= 1) lc += __shfl_down(lc, off);
    __syncthreads();
    if (lane == 0 && lc) atomicAdd(&cnt_sh, lc);

    auto cas_shfl = [&](float& rr, int i, unsigned k, unsigned j) {
        float o = __shfl_xor(rr, (int)j);
        bool lower = ((lane & (int)j) == 0);
        bool desc  = ((i & (int)k) == 0);
        rr = (lower == desc) ? fmaxf(rr, o) : fminf(rr, o);
    };
    #pragma unroll
    for (unsigned k = 2; k <= 64; k <<= 1)
        #pragma unroll
        for (unsigned j = k >> 1; j; j >>= 1) { cas_shfl(r0, i0, k, j); cas_shfl(r1, i1, k, j); }
    #pragma unroll
    for (unsigned k = 128; k <= 1024; k <<= 1) {
        #pragma unroll
        for (unsigned j = k >> 1; j >= 128; j >>= 1) {
            __syncthreads();
            sx[i0] = r0; sx[i1] = r1;
            __syncthreads();
            float o0 = sx[i0 ^ (int)j], o1 = sx[i1 ^ (int)j];
            bool lower = ((i0 & (int)j) == 0);
            bool desc  = ((i0 & (int)k) == 0);
            r0 = (lower == desc) ? fmaxf(r0, o0) : fminf(r0, o0);
            r1 = (lower == desc) ? fmaxf(r1, o1) : fminf(r1, o1);
        }
        {
            bool desc = ((i0 & (int)k) == 0);
            float a = fmaxf(r0, r1), b = fminf(r0, r1);
            r0 = desc ? a : b;
            r1 = desc ? b : a;
        }
        #pragma unroll
        for (unsigned j = 32; j; j >>= 1) { cas_shfl(r0, i0, k, j); cas_shfl(r1, i1, k, j); }
    }

    if (i1 >= N) r1 = 0.0f;
    float incl0 = r0;
    #pragma unroll
    for (int off = 1; off < 64; off <<= 1) {
        float y = __shfl_up(incl0, off);
        if (lane >= off) incl0 += y;
    }
    float tot0 = __shfl(incl0, 63);
    float incl1 = r1;
    #pragma unroll
    for (int off = 1; off < 64; off <<= 1) {
        float y = __shfl_up(incl1, off);
        if (lane >= off) incl1 += y;
    }
    if (lane == 63) wtot[w] = incl0 + incl1;
    __syncthreads();
    float base = 0.0f;
    #pragma unroll
    for (int u = 0; u < 8; ++u) { float t = wtot[u]; if (u < w) base += t; }
    if (tid == 0) S[0] = 0.0f;
    S[i0 + 1] = base + incl0;
    S[i1 + 1] = base + tot0 + incl1;
    __syncthreads();

    const int p   = cnt_sh;
    const int len = N - p;
    float minv = INFINITY;
    for (int j = tid; j <= p; j += NTH1) {
        const float  Sj = S[j];
        const float* Sp = &S[p + 1];
        const float* rp = &rcp[p - j];
        const float  cj = 0.5f * (float)(j + p) - (float)N;
        float maxv = -INFINITY;
        #pragma unroll 8
        for (int it = 0; it < len; ++it) {
            float mm = fmaf(Sp[it] - Sj, rp[it], cj + 0.5f * (float)it);
            maxv = fmaxf(maxv, mm);
        }
        minv = fminf(minv, maxv);
    }
    #pragma unroll
    for (int off = 32; off; off >>= 1) minv = fminf(minv, __shfl_down(minv, off));
    if (lane == 0) red[w] = minv;
    __syncthreads();
    if (tid == 0) {
        float sol = red[0];
        #pragma unroll
        for (int u = 1; u < 8; ++u) sol = fminf(sol, red[u]);
        float rank_label = tval - sol;
        float loss = fmaxf(0.0f, (float)(N - 5 + 1) - rank_label);
        atomicAdd(d_out, loss / (float)nrows);
    }
}

extern "C" void kernel_launch(void* const* d_in, const int* in_sizes, int n_in,
                              void* d_out, int out_size, void* d_ws, size_t ws_size,
                              hipStream_t stream) {
    (void)n_in;
    const float* mat    = (const float*)d_in[0];
    const int*   target = (const int*)d_in[1];
    float*       out    = (float*)d_out;
    const int    nrows  = in_sizes[1];   // 64

    const size_t need = (size_t)(META + 256) * sizeof(float);
    if (nrows == 64 && ws_size >= need) {
        float*    ws = (float*)d_ws;
        float*    tv = ws + META + 64;
        unsigned* mr = (unsigned*)(ws + META + 128);
        k1_sort_scan<<<nrows, NTH1, 0, stream>>>(mat, target, ws);
        dim3 g2(MSLICE, nrows);
        k2_minmax<<<g2, NTH2, 0, stream>>>(ws, mr);
        k3_loss<<<1, 64, 0, stream>>>(mr, tv, out, nrows);
    } else {
        hipMemsetAsync(out, 0, sizeof(float) * out_size, stream);
        topk_loss_mono<<<nrows, NTH1, 0, stream>>>(mat, target, out, nrows);
    }
}